// Round 3
// baseline (332.231 us; speedup 1.0000x reference)
//
#include <hip/hip_runtime.h>

#define W_ 320
#define H_ 96
#define B_ 4
#define C_ 256
#define CS (H_ * W_)          // 30720
#define MT_ 64                // M per block (queries)  -> acc[2][5] = 40 regs/wave
#define PITCHD 17             // dwords per LDS tile row (odd -> bank-spread)
#define GA 24                 // A physical row-group stride: 24*17 % 32 == 24 (order-4)
#define GB 88                 // B physical row-group stride: 88*17 % 32 == 24 (order-4)
#define ADW (( (3*GA) + 16) * PITCHD)   // A region: 88 rows * 17 = 1496 dwords
#define BDW (( (3*GB) + 80) * PITCHD)   // B region: 344 rows * 17 = 5848 dwords
#define TBUFD (ADW + BDW)               // 7344 dwords per K-step buffer (29376 B)
#define PITCHC 321            // corr chunk row pitch (shorts)

typedef __attribute__((ext_vector_type(8))) short short8;
typedef __attribute__((ext_vector_type(4))) float f32x4;

static __device__ __forceinline__ unsigned f2bf(float f) {
  unsigned u = __builtin_bit_cast(unsigned, f);
  return (u + 0x7FFFu + ((u >> 16) & 1u)) >> 16;   // RNE fp32 -> bf16
}
// hardware packed RNE convert: lo = a, hi = b (identical bits to f2bf pair)
static __device__ __forceinline__ unsigned pk(float a, float b) {
  unsigned r;
  asm("v_cvt_pk_bf16_f32 %0, %1, %2" : "=v"(r) : "v"(a), "v"(b));
  return r;
}
static __device__ __forceinline__ float bf2f(unsigned short h) {
  return __builtin_bit_cast(float, (unsigned)h << 16);
}
// Barrier without vmcnt drain: LDS visibility via lgkmcnt(0); prefetch global
// loads stay in flight across it.
static __device__ __forceinline__ void bar_keepvm() {
  asm volatile("s_waitcnt lgkmcnt(0)\n\ts_barrier" ::: "memory");
}

union Frag { short8 s; uint4 u; };

// One block = (b,hh, fifth-of-row): M=64 queries x N=320 cols x K=256 channels.
// Wave tile 32x80 -> acc = 40 AGPRs. 2-deep register prefetch (2x24 regs) puts
// total at ~128 -> still 4 waves/SIMD (2 blocks/CU), loads get ~2 halfsteps
// of latency slack and vmcnt never drains in the K-loop.
__global__ __launch_bounds__(512, 4) void corr_row(
    const float* __restrict__ fmap1, const float* __restrict__ fmap2,
    const float* __restrict__ cents, float* __restrict__ out)
{
  __shared__ __align__(16) unsigned short smem[2 * 2 * TBUFD];  // 58752 B
  unsigned short* Csh = smem;   // epilogue: 64*321 = 20544 shorts (fits)

  const int tid  = threadIdx.x;
  const int lane = tid & 63;
  const int wv   = tid >> 6;      // 0..7
  const int mw   = wv >> 2;       // 0..1  (M half: 32 rows)
  const int nw   = wv & 3;        // 0..3  (N quarter: 80 cols)
  const int m    = lane & 15;
  const int quad = lane >> 4;

  // XCD-pinned decode: the 5 blocks sharing a (b,hh) row all have the same
  // blockIdx%8 and adjacent per-XCD dispatch slots -> fmap2 row (327 KB)
  // served from one XCD's L2 despite 5x staging redundancy.
  const int i   = blockIdx.x;          // 0..1919
  const int xcd = i & 7;
  const int t   = i >> 3;              // 0..239
  const int r   = (t / 5) * 8 + xcd;   // 0..383 == b*H_+hh
  const int mb  = t % 5;
  const int b   = r / H_;
  const int hh  = r % H_;
  const int q0  = mb * MT_;

  const float* Abase = fmap1 + ((size_t)b * C_ * H_ + hh) * W_ + q0; // + c*CS + v
  const float* Bbase = fmap2 + ((size_t)b * C_ * H_ + hh) * W_;      // + c*CS + v

  // ---- per-thread staging slots (3): item id = tid + 512*p, 1536 items/step ----
  // A items (it<256):   c2 = it/16, k = it%16  (A: 64 rows, 16 row-groups)
  // B items (it>=256):  c2 = ib/80, k = ib%80  (B: 320 rows, 80 row-groups)
  // LDS physical row permutation: p(4k+j) = j*G + k  (G: GA=24 / GB=88).
  // Dword-column rotation c2' = (c2 + 4*(k&3)) & 15 kills the residual
  // 17*dl + dc2 = 0 (mod 32) write aliases; reads un-rotate via
  // quad' = (quad + (m>>2)) & 3 (k = {mw*8|nw*20} + {mt|nt}*4 + (m>>2), so
  // k&3 == (m>>2) for every tile of both operands).
  const float* sp[3];
  int dsti[3];
#pragma unroll
  for (int p = 0; p < 3; ++p) {
    int it = tid + 512 * p;
    bool isA = (it < 256);
    int c2, k;
    if (isA) { c2 = it >> 4; k = it & 15; }
    else     { int ib = it - 256; c2 = ib / 80; k = ib % 80; }
    sp[p]   = (isA ? Abase : Bbase) + (size_t)(2 * c2) * CS + 4 * k;
    dsti[p] = k * PITCHD + ((c2 + 4 * (k & 3)) & 15) + (isA ? 0 : ADW);
  }
  // j-stride (physical rows per +1 of j, times pitch): A 24*17=408, B 88*17=1496
  const int jst0 = (tid < 256) ? GA * PITCHD : GB * PITCHD;   // wave-uniform

  f32x4 acc[2][5] = {};
  Frag fa[2];
  float4 ga[3][2], gb[3][2];   // 2-deep prefetch: two independent load sets

  auto issue = [&](int s, float4 (*g)[2]) {
#pragma unroll
    for (int p = 0; p < 3; ++p) {
      const float* q = sp[p] + (size_t)(s * 32) * CS;
      g[p][0] = *(const float4*)q;
      g[p][1] = *(const float4*)(q + CS);
    }
  };
  auto stage = [&](int s, float4 (*g)[2]) {
    unsigned* buf = (unsigned*)smem + (s & 1) * TBUFD;
#pragma unroll
    for (int p = 0; p < 3; ++p) {
      unsigned* d = buf + dsti[p];
      const int st = (p == 0) ? jst0 : GB * PITCHD;
      d[0]      = pk(g[p][0].x, g[p][1].x);
      d[st]     = pk(g[p][0].y, g[p][1].y);
      d[2 * st] = pk(g[p][0].z, g[p][1].z);
      d[3 * st] = pk(g[p][0].w, g[p][1].w);
    }
  };

  // permuted physical-row read bases (mt/nt add 4 logical row-groups per step)
  const int rotq4 = ((quad + (m >> 2)) & 3) * 4;
  const int pbA = ((m & 3) * GA + mw * 8 + (m >> 2)) * PITCHD + rotq4;
  const int pbB = ADW + ((m & 3) * GB + nw * 20 + (m >> 2)) * PITCHD + rotq4;

  auto fragmfma = [&](int s) {
    const unsigned* buf = (const unsigned*)smem + (s & 1) * TBUFD;
#pragma unroll
    for (int mt = 0; mt < 2; ++mt) {
      const unsigned* pa = buf + pbA + mt * 4 * PITCHD;
      fa[mt].u.x = pa[0]; fa[mt].u.y = pa[1]; fa[mt].u.z = pa[2]; fa[mt].u.w = pa[3];
    }
#pragma unroll
    for (int nt = 0; nt < 5; ++nt) {
      const unsigned* pb = buf + pbB + nt * 4 * PITCHD;
      Frag fb;
      fb.u.x = pb[0]; fb.u.y = pb[1]; fb.u.z = pb[2]; fb.u.w = pb[3];
#pragma unroll
      for (int mt = 0; mt < 2; ++mt)
        acc[mt][nt] = __builtin_amdgcn_mfma_f32_16x16x32_bf16(
            fa[mt].s, fb.s, acc[mt][nt], 0, 0, 0);
    }
  };

  // ---- K-loop: 2-deep prefetch, one raw barrier per half-step.
  // At stage(hs): 12 loads outstanding (g(hs), g(hs+1)); compiler waits
  // vmcnt(6) for g(hs) -> never drains to 0. g(hs) was issued ~2 halfsteps
  // earlier (after bar(hs-2)). Buffer reuse race-free: buf[hs&1] last read
  // by fragmfma(hs-2), which finished before bar(hs-1).
  issue(0, ga);
  issue(1, gb);
#pragma unroll
  for (int hs = 0; hs < 8; ++hs) {
    if (hs & 1) stage(hs, gb); else stage(hs, ga);
    bar_keepvm();
    if (hs < 6) { if (hs & 1) issue(hs + 2, gb); else issue(hs + 2, ga); }
    __builtin_amdgcn_s_setprio(1);
    fragmfma(hs);
    __builtin_amdgcn_s_setprio(0);
  }

  // ---- epilogue: single 64-query chunk through Csh (unions with buffers) ----
  __syncthreads();   // K-loop frag reads done
  // C/D layout: col = lane&15, row = quad*4 + reg
#pragma unroll
  for (int mt = 0; mt < 2; ++mt)
#pragma unroll
    for (int nt = 0; nt < 5; ++nt)
#pragma unroll
      for (int rr = 0; rr < 4; ++rr)
        Csh[(mw * 32 + mt * 16 + quad * 4 + rr) * PITCHC + nw * 80 + nt * 16 + m] =
            (unsigned short)f2bf(acc[mt][nt][rr] * 0.0625f);
  __syncthreads();
  if (tid < 256) {
    const int l = tid >> 6;          // level
    const int q = tid & 63;          // query within block
    const int qg = q0 + q;
    const int Wl  = W_ >> l;
    const int mul = 1 << l;
    const float invm = 1.0f / (float)mul;
    const float cent = cents[(b * H_ + hh) * W_ + qg];
    const float cl = cent * invm;    // exact pow2 scaling == iterated /2
    const unsigned short* crow = Csh + q * PITCHC;
    float* op = out + ((size_t)(b * 36 + l * 9) * H_ + hh) * W_ + qg;
#pragma unroll
    for (int j = 0; j < 9; ++j) {
      float x  = cl + (float)(j - 4);
      float x0 = floorf(x);
      float t  = x - x0;
      int i0 = (int)x0;
      float v0 = 0.0f, v1 = 0.0f;
      if (i0 >= 0 && i0 < Wl) {
        float s2 = 0.0f;
        for (int d = 0; d < mul; ++d) s2 += bf2f(crow[i0 * mul + d]);
        v0 = s2 * invm;
      }
      int i1 = i0 + 1;
      if (i1 >= 0 && i1 < Wl) {
        float s2 = 0.0f;
        for (int d = 0; d < mul; ++d) s2 += bf2f(crow[i1 * mul + d]);
        v1 = s2 * invm;
      }
      op[(size_t)j * H_ * W_] = v0 * (1.0f - t) + v1 * t;
    }
  }
}

extern "C" void kernel_launch(void* const* d_in, const int* in_sizes, int n_in,
                              void* d_out, int out_size, void* d_ws, size_t ws_size,
                              hipStream_t stream) {
  const float* fmap1 = (const float*)d_in[0];
  const float* fmap2 = (const float*)d_in[1];
  const float* cents = (const float*)d_in[2];
  float* out = (float*)d_out;
  corr_row<<<dim3(1920), 512, 0, stream>>>(fmap1, fmap2, cents, out);
}

// Round 4
// 287.170 us; speedup vs baseline: 1.1569x; 1.1569x over previous
//
#include <hip/hip_runtime.h>

#define W_ 320
#define H_ 96
#define B_ 4
#define C_ 256
#define CS (H_ * W_)          // 30720
#define MT_ 64                // M per block (queries)
#define PITCHD 17             // dwords per LDS tile row (odd -> bank-spread)
#define GA 24                 // A physical row-group stride: 24*17 % 32 == 24 (order-4)
#define GB 88                 // B physical row-group stride: 88*17 % 32 == 24 (order-4)
#define ADW (88 * PITCHD)     // A region: 88 rows * 17 = 1496 dwords
#define BDW (344 * PITCHD)    // B region: 344 rows * 17 = 5848 dwords
#define TBUFD (ADW + BDW)     // 7344 dwords per K-step buffer (29376 B)
#define PITCHC 321            // corr chunk row pitch (shorts)

typedef __attribute__((ext_vector_type(8))) short short8;
typedef __attribute__((ext_vector_type(4))) float f32x4;

static __device__ __forceinline__ unsigned f2bf(float f) {
  unsigned u = __builtin_bit_cast(unsigned, f);
  return (u + 0x7FFFu + ((u >> 16) & 1u)) >> 16;   // RNE fp32 -> bf16
}
// hardware packed RNE convert: lo = a, hi = b (identical bits to f2bf pair)
static __device__ __forceinline__ unsigned pk(float a, float b) {
  unsigned r;
  asm("v_cvt_pk_bf16_f32 %0, %1, %2" : "=v"(r) : "v"(a), "v"(b));
  return r;
}
static __device__ __forceinline__ float bf2f(unsigned short h) {
  return __builtin_bit_cast(float, (unsigned)h << 16);
}
// Barrier without vmcnt drain: LDS visibility via lgkmcnt(0); prefetch global
// loads stay in flight across it.
static __device__ __forceinline__ void bar_keepvm() {
  asm volatile("s_waitcnt lgkmcnt(0)\n\ts_barrier" ::: "memory");
}
// wave-uniform 64-bit pointer -> SGPR pair (saves VGPR address pairs)
static __device__ __forceinline__ const float* uniform_ptr(const float* p) {
  unsigned long long u = (unsigned long long)p;
  unsigned lo = __builtin_amdgcn_readfirstlane((unsigned)u);
  unsigned hi = __builtin_amdgcn_readfirstlane((unsigned)(u >> 32));
  return (const float*)(((unsigned long long)hi << 32) | lo);
}

union Frag { short8 s; uint4 u; };

// One block = (b,hh, fifth-of-row): M=64 x N=320 x K=256, 1024 threads,
// 16 waves in a 4x4 grid of 16x80 tiles -> acc[5] = 20 regs/wave.
// __launch_bounds__(1024,8) forces <=64 regs -> 2 blocks/CU = 32 waves/CU
// (100% wave occupancy), two independent 16-wave barrier domains.
__global__ __launch_bounds__(1024, 8) void corr_row(
    const float* __restrict__ fmap1, const float* __restrict__ fmap2,
    const float* __restrict__ cents, float* __restrict__ out)
{
  __shared__ __align__(16) unsigned short smem[2 * 2 * TBUFD];  // 58752 B
  unsigned short* Csh = smem;   // epilogue: 64*321 = 20544 shorts (fits)

  const int tid  = threadIdx.x;
  const int lane = tid & 63;
  const int wv   = tid >> 6;      // 0..15
  const int mw   = wv >> 2;       // 0..3  (M quarter: 16 rows)
  const int nw   = wv & 3;        // 0..3  (N quarter: 80 cols)
  const int m    = lane & 15;
  const int quad = lane >> 4;

  // XCD-pinned decode: the 5 blocks sharing a (b,hh) row all have the same
  // blockIdx%8 and adjacent per-XCD dispatch slots -> fmap2 row lives in
  // that XCD's L2 despite 5x staging redundancy.
  const int i   = blockIdx.x;          // 0..1919
  const int xcd = i & 7;
  const int t   = i >> 3;              // 0..239
  const int r   = (t / 5) * 8 + xcd;   // 0..383 == b*H_+hh
  const int mb  = t % 5;
  const int b   = r / H_;
  const int hh  = r % H_;
  const int q0  = mb * MT_;

  const float* Abase = fmap1 + ((size_t)b * C_ * H_ + hh) * W_ + q0; // + c*CS + v
  const float* Bbase = fmap2 + ((size_t)b * C_ * H_ + hh) * W_;      // + c*CS + v

  // ---- per-thread staging slots (2): item id = tid + 1024*p, 1536 items/step ----
  // A items (it<256):   c2 = it/16, k = it%16  (A: 64 rows, 16 row-groups)
  // B items (it>=256):  c2 = ib/80, k = ib%80  (B: 320 rows, 80 row-groups)
  // LDS physical row permutation: p(4k+j) = j*G + k  (G: GA=24 / GB=88).
  // Dword-column rotation c2' = (c2 + 4*(k&3)) & 15; reads un-rotate via
  // quad' = (quad + (m>>2)) & 3 (all read row-group terms besides (m>>2)
  // are multiples of 4 for both operands).
  // isA boundary (it<256) is wave-aligned -> base pointers wave-uniform.
  const float* sb0 = uniform_ptr((tid < 256) ? Abase : Bbase);  // slot 0 base
  const float* sb1 = uniform_ptr(Bbase);                        // slot 1 base (always B)
  int off0, off1, dsti0, dsti1;
  {
    int it = tid;
    bool isA = (it < 256);
    int c2, k;
    if (isA) { c2 = it >> 4; k = it & 15; }
    else     { int ib = it - 256; c2 = ib / 80; k = ib % 80; }
    off0  = 2 * c2 * CS + 4 * k;
    dsti0 = k * PITCHD + ((c2 + 4 * (k & 3)) & 15) + (isA ? 0 : ADW);
    int it1 = tid + 1024;              // >=1024 -> always B
    int ib1 = it1 - 256;
    int c21 = ib1 / 80, k1 = ib1 % 80;
    off1  = 2 * c21 * CS + 4 * k1;
    dsti1 = k1 * PITCHD + ((c21 + 4 * (k1 & 3)) & 15) + ADW;
  }
  const bool act1 = (tid < 512);
  const int jst0 = (tid < 256) ? GA * PITCHD : GB * PITCHD;   // wave-uniform

  f32x4 acc[5] = {};
  Frag fa;
  float4 g[2][2];

  auto issue = [&](int s) {
    const float* q0p = sb0 + off0 + s * 32 * CS;
    g[0][0] = *(const float4*)q0p;
    g[0][1] = *(const float4*)(q0p + CS);
    if (act1) {
      const float* q1p = sb1 + off1 + s * 32 * CS;
      g[1][0] = *(const float4*)q1p;
      g[1][1] = *(const float4*)(q1p + CS);
    }
  };
  auto stage = [&](int s) {
    unsigned* buf = (unsigned*)smem + (s & 1) * TBUFD;
    {
      unsigned* d = buf + dsti0;
      const int st = jst0;
      d[0]      = pk(g[0][0].x, g[0][1].x);
      d[st]     = pk(g[0][0].y, g[0][1].y);
      d[2 * st] = pk(g[0][0].z, g[0][1].z);
      d[3 * st] = pk(g[0][0].w, g[0][1].w);
    }
    if (act1) {
      unsigned* d = buf + dsti1;
      const int st = GB * PITCHD;
      d[0]      = pk(g[1][0].x, g[1][1].x);
      d[st]     = pk(g[1][0].y, g[1][1].y);
      d[2 * st] = pk(g[1][0].z, g[1][1].z);
      d[3 * st] = pk(g[1][0].w, g[1][1].w);
    }
  };

  // permuted physical-row read bases (nt adds 4 logical row-groups per step)
  const int rotq4 = ((quad + (m >> 2)) & 3) * 4;
  const int pbA = ((m & 3) * GA + mw * 4 + (m >> 2)) * PITCHD + rotq4;
  const int pbB = ADW + ((m & 3) * GB + nw * 20 + (m >> 2)) * PITCHD + rotq4;

  auto fragmfma = [&](int s) {
    const unsigned* buf = (const unsigned*)smem + (s & 1) * TBUFD;
    {
      const unsigned* pa = buf + pbA;
      fa.u.x = pa[0]; fa.u.y = pa[1]; fa.u.z = pa[2]; fa.u.w = pa[3];
    }
#pragma unroll
    for (int nt = 0; nt < 5; ++nt) {
      const unsigned* pb = buf + pbB + nt * 4 * PITCHD;
      Frag fb;
      fb.u.x = pb[0]; fb.u.y = pb[1]; fb.u.z = pb[2]; fb.u.w = pb[3];
      acc[nt] = __builtin_amdgcn_mfma_f32_16x16x32_bf16(
          fa.s, fb.s, acc[nt], 0, 0, 0);
    }
  };

  // ---- K-loop: 1-deep register prefetch, one raw barrier per half-step.
  // issue(hs+1) right after the barrier -> loads in flight across fragmfma(hs);
  // stage(hs) writes buf[hs&1], last read by fragmfma(hs-2) before bar(hs-1).
  // Cross-domain TLP (2 x 16-wave blocks/CU) covers residual latency.
  issue(0);
#pragma unroll
  for (int hs = 0; hs < 8; ++hs) {
    stage(hs);
    bar_keepvm();
    if (hs < 7) issue(hs + 1);
    __builtin_amdgcn_s_setprio(1);
    fragmfma(hs);
    __builtin_amdgcn_s_setprio(0);
  }

  // ---- epilogue: single 64-query chunk through Csh (unions with buffers) ----
  __syncthreads();   // K-loop frag reads done
  // C/D layout: col = lane&15, row = quad*4 + reg. 16 waves cover 64 rows.
#pragma unroll
  for (int nt = 0; nt < 5; ++nt)
#pragma unroll
    for (int rr = 0; rr < 4; ++rr)
      Csh[(mw * 16 + quad * 4 + rr) * PITCHC + nw * 80 + nt * 16 + m] =
          (unsigned short)f2bf(acc[nt][rr] * 0.0625f);
  __syncthreads();
  if (tid < 512) {
    const int l  = tid >> 7;         // level 0..3
    const int jh = (tid >> 6) & 1;   // j-half: 0 -> j 0..4, 1 -> j 5..8
    const int q  = tid & 63;         // query within block
    const int qg = q0 + q;
    const int Wl  = W_ >> l;
    const int mul = 1 << l;
    const float invm = 1.0f / (float)mul;
    const float cent = cents[(b * H_ + hh) * W_ + qg];
    const float cl = cent * invm;    // exact pow2 scaling == iterated /2
    const unsigned short* crow = Csh + q * PITCHC;
    float* op = out + ((size_t)(b * 36 + l * 9) * H_ + hh) * W_ + qg;
    const int j0 = jh * 5, j1 = jh ? 9 : 5;
    for (int j = j0; j < j1; ++j) {
      float x  = cl + (float)(j - 4);
      float x0 = floorf(x);
      float t  = x - x0;
      int i0 = (int)x0;
      float v0 = 0.0f, v1 = 0.0f;
      if (i0 >= 0 && i0 < Wl) {
        float s2 = 0.0f;
        for (int d = 0; d < mul; ++d) s2 += bf2f(crow[i0 * mul + d]);
        v0 = s2 * invm;
      }
      int i1 = i0 + 1;
      if (i1 >= 0 && i1 < Wl) {
        float s2 = 0.0f;
        for (int d = 0; d < mul; ++d) s2 += bf2f(crow[i1 * mul + d]);
        v1 = s2 * invm;
      }
      op[(size_t)j * H_ * W_] = v0 * (1.0f - t) + v1 * t;
    }
  }
}

extern "C" void kernel_launch(void* const* d_in, const int* in_sizes, int n_in,
                              void* d_out, int out_size, void* d_ws, size_t ws_size,
                              hipStream_t stream) {
  const float* fmap1 = (const float*)d_in[0];
  const float* fmap2 = (const float*)d_in[1];
  const float* cents = (const float*)d_in[2];
  float* out = (float*)d_out;
  corr_row<<<dim3(1920), 1024, 0, stream>>>(fmap1, fmap2, cents, out);
}